// Round 6
// baseline (101.165 us; speedup 1.0000x reference)
//
#include <hip/hip_runtime.h>

// ECT layer: ect[b,s,t] = sum_{i: batch[i]==b} sigmoid(lin[s] - <x_i, v_t>)
// N=200000, F=3, T=32, S=32, B=128. Output [B,S,T] float32.
//
// sigmoid(lin - nh) = 1 / (1 + exp(nh) * exp(-lin))
//   -> one exp2 per (point, t), shared across all 32 s; per-s cost = FMA+rcp+add.

#define CHUNK 128
#define TT 32
#define SS 32
#define LOG2E 1.4426950408889634f

__global__ void zero_out_kernel(float* __restrict__ out, int n) {
    int i = blockIdx.x * blockDim.x + threadIdx.x;
    if (i < n) out[i] = 0.0f;
}

__global__ __launch_bounds__(256) void ect_kernel(
    const float* __restrict__ x, const int* __restrict__ batch,
    const float* __restrict__ v, const float* __restrict__ lin,
    float* __restrict__ out, int N) {
    __shared__ float sx[CHUNK * 3];
    __shared__ int   sb[CHUNK];

    const int tid  = threadIdx.x;
    const int base = blockIdx.x * CHUNK;
    const int cnt  = min(CHUNK, N - base);
    if (cnt <= 0) return;  // uniform across block

    // Stage chunk: x rows (12B/point) + batch ids, coalesced.
    for (int idx = tid; idx < cnt * 3; idx += 256) sx[idx] = x[base * 3 + idx];
    for (int idx = tid; idx < cnt;     idx += 256) sb[idx] = batch[base + idx];
    __syncthreads();

    // Thread owns direction t and 4 thresholds s_base..s_base+3.
    const int t      = tid & 31;
    const int s_base = (tid >> 5) * 4;
    const float v0 = v[t], v1 = v[TT + t], v2 = v[2 * TT + t];
    const float c0 = __builtin_amdgcn_exp2f(-lin[s_base + 0] * LOG2E);
    const float c1 = __builtin_amdgcn_exp2f(-lin[s_base + 1] * LOG2E);
    const float c2 = __builtin_amdgcn_exp2f(-lin[s_base + 2] * LOG2E);
    const float c3 = __builtin_amdgcn_exp2f(-lin[s_base + 3] * LOG2E);

    const int out_off = s_base * TT + t;  // + b*S*T

    float a0 = 0.f, a1 = 0.f, a2 = 0.f, a3 = 0.f;

    if (sb[0] == sb[cnt - 1]) {
        // Hot path: whole chunk belongs to one graph -> branch-free, unrollable.
        #pragma unroll 4
        for (int j = 0; j < cnt; ++j) {
            float nh = fmaf(sx[3 * j + 2], v2,
                       fmaf(sx[3 * j + 1], v1, sx[3 * j] * v0));
            float E = __builtin_amdgcn_exp2f(nh * LOG2E);
            a0 += __builtin_amdgcn_rcpf(fmaf(E, c0, 1.0f));
            a1 += __builtin_amdgcn_rcpf(fmaf(E, c1, 1.0f));
            a2 += __builtin_amdgcn_rcpf(fmaf(E, c2, 1.0f));
            a3 += __builtin_amdgcn_rcpf(fmaf(E, c3, 1.0f));
        }
        float* o = out + sb[0] * (SS * TT) + out_off;
        atomicAdd(o +  0, a0);
        atomicAdd(o + 32, a1);
        atomicAdd(o + 64, a2);
        atomicAdd(o + 96, a3);
    } else {
        // Chunk spans a graph boundary (rare): flush on transition.
        int cur_b = sb[0];
        for (int j = 0; j < cnt; ++j) {
            int b = sb[j];  // wave-uniform
            if (b != cur_b) {
                float* o = out + cur_b * (SS * TT) + out_off;
                atomicAdd(o +  0, a0);
                atomicAdd(o + 32, a1);
                atomicAdd(o + 64, a2);
                atomicAdd(o + 96, a3);
                a0 = a1 = a2 = a3 = 0.f;
                cur_b = b;
            }
            float nh = fmaf(sx[3 * j + 2], v2,
                       fmaf(sx[3 * j + 1], v1, sx[3 * j] * v0));
            float E = __builtin_amdgcn_exp2f(nh * LOG2E);
            a0 += __builtin_amdgcn_rcpf(fmaf(E, c0, 1.0f));
            a1 += __builtin_amdgcn_rcpf(fmaf(E, c1, 1.0f));
            a2 += __builtin_amdgcn_rcpf(fmaf(E, c2, 1.0f));
            a3 += __builtin_amdgcn_rcpf(fmaf(E, c3, 1.0f));
        }
        float* o = out + cur_b * (SS * TT) + out_off;
        atomicAdd(o +  0, a0);
        atomicAdd(o + 32, a1);
        atomicAdd(o + 64, a2);
        atomicAdd(o + 96, a3);
    }
}

extern "C" void kernel_launch(void* const* d_in, const int* in_sizes, int n_in,
                              void* d_out, int out_size, void* d_ws, size_t ws_size,
                              hipStream_t stream) {
    const float* x     = (const float*)d_in[0];  // [N,3]
    const int*   batch = (const int*)d_in[1];    // [N]
    const float* v     = (const float*)d_in[2];  // [3,32]
    const float* lin   = (const float*)d_in[3];  // [32]
    float* out = (float*)d_out;                  // [128,32,32]

    const int N = in_sizes[1];

    zero_out_kernel<<<(out_size + 255) / 256, 256, 0, stream>>>(out, out_size);

    const int nblocks = (N + CHUNK - 1) / CHUNK;
    ect_kernel<<<nblocks, 256, 0, stream>>>(x, batch, v, lin, out, N);
}

// Round 8
// 97.945 us; speedup vs baseline: 1.0329x; 1.0329x over previous
//
#include <hip/hip_runtime.h>

// ECT: ect[b,s,t] = sum_{i: batch[i]==b} sigmoid(lin[s] - <x_i, v_t>)
// N=200000, F=3, T=32, S=32, B=128. Output [B,S,T] f32.
//
// sigmoid(lin - nh) = 1/(1 + E*c),  E = exp2(x . (v*log2e)),  c = exp(-lin).
// Paired reciprocal: r = rcp(w0*w1) -> sig0 = r*w1, sig1 = r*w0
//   (trades 1 trans (8 cyc) for ~1 VALU (2 cyc); trans/point/thread 5 -> 3).
// All x/batch accesses in the hot loop are BLOCK-UNIFORM -> scalar loads
// (no LDS staging: round-6 profile showed the LDS broadcast reads were
//  ~23 us of the 44 us kernel).

#define CHUNK 128
#define TT 32
#define SS 32
#define LOG2E 1.4426950408889634f

__global__ void zero_out_kernel(float* __restrict__ out, int n) {
    int i = blockIdx.x * blockDim.x + threadIdx.x;
    if (i < n) out[i] = 0.0f;
}

__global__ __launch_bounds__(256) void ect_kernel(
    const float* __restrict__ x, const int* __restrict__ batch,
    const float* __restrict__ v, const float* __restrict__ lin,
    float* __restrict__ out, int N) {

    const int tid  = threadIdx.x;
    const int base = blockIdx.x * CHUNK;
    const int cnt  = min(CHUNK, N - base);
    if (cnt <= 0) return;  // uniform across block

    const int t      = tid & 31;
    const int s_base = (tid >> 5) * 4;

    // Pre-scaled direction so E = exp2(<x, v'>) needs no extra multiply.
    const float v0 = v[t] * LOG2E;
    const float v1 = v[TT + t] * LOG2E;
    const float v2 = v[2 * TT + t] * LOG2E;
    const float c0 = __builtin_amdgcn_exp2f(-lin[s_base + 0] * LOG2E);
    const float c1 = __builtin_amdgcn_exp2f(-lin[s_base + 1] * LOG2E);
    const float c2 = __builtin_amdgcn_exp2f(-lin[s_base + 2] * LOG2E);
    const float c3 = __builtin_amdgcn_exp2f(-lin[s_base + 3] * LOG2E);

    const float* __restrict__ xc = x + 3 * (size_t)base;  // block-uniform base
    const int*   __restrict__ bc = batch + base;

    const int out_off = s_base * TT + t;  // + b*S*T

    float a0 = 0.f, a1 = 0.f, a2 = 0.f, a3 = 0.f;

    const int b_first = bc[0];
    const int b_last  = bc[cnt - 1];

    if (b_first == b_last) {
        // Hot path: whole chunk in one graph. All loads uniform -> s_load.
        #pragma unroll 4
        for (int j = 0; j < cnt; ++j) {
            float s0 = xc[3 * j], s1 = xc[3 * j + 1], s2 = xc[3 * j + 2];
            float E  = __builtin_amdgcn_exp2f(fmaf(s2, v2, fmaf(s1, v1, s0 * v0)));
            float w0 = fmaf(E, c0, 1.0f);
            float w1 = fmaf(E, c1, 1.0f);
            float r01 = __builtin_amdgcn_rcpf(w0 * w1);
            a0 = fmaf(r01, w1, a0);
            a1 = fmaf(r01, w0, a1);
            float w2 = fmaf(E, c2, 1.0f);
            float w3 = fmaf(E, c3, 1.0f);
            float r23 = __builtin_amdgcn_rcpf(w2 * w3);
            a2 = fmaf(r23, w3, a2);
            a3 = fmaf(r23, w2, a3);
        }
        float* o = out + b_first * (SS * TT) + out_off;
        atomicAdd(o +  0, a0);
        atomicAdd(o + 32, a1);
        atomicAdd(o + 64, a2);
        atomicAdd(o + 96, a3);
    } else {
        // Chunk spans graph boundary (~13% of chunks): flush on transition.
        int cur_b = b_first;
        for (int j = 0; j < cnt; ++j) {
            int b = bc[j];  // uniform
            if (b != cur_b) {
                float* o = out + cur_b * (SS * TT) + out_off;
                atomicAdd(o +  0, a0);
                atomicAdd(o + 32, a1);
                atomicAdd(o + 64, a2);
                atomicAdd(o + 96, a3);
                a0 = a1 = a2 = a3 = 0.f;
                cur_b = b;
            }
            float s0 = xc[3 * j], s1 = xc[3 * j + 1], s2 = xc[3 * j + 2];
            float E  = __builtin_amdgcn_exp2f(fmaf(s2, v2, fmaf(s1, v1, s0 * v0)));
            float w0 = fmaf(E, c0, 1.0f);
            float w1 = fmaf(E, c1, 1.0f);
            float r01 = __builtin_amdgcn_rcpf(w0 * w1);
            a0 = fmaf(r01, w1, a0);
            a1 = fmaf(r01, w0, a1);
            float w2 = fmaf(E, c2, 1.0f);
            float w3 = fmaf(E, c3, 1.0f);
            float r23 = __builtin_amdgcn_rcpf(w2 * w3);
            a2 = fmaf(r23, w3, a2);
            a3 = fmaf(r23, w2, a3);
        }
        float* o = out + cur_b * (SS * TT) + out_off;
        atomicAdd(o +  0, a0);
        atomicAdd(o + 32, a1);
        atomicAdd(o + 64, a2);
        atomicAdd(o + 96, a3);
    }
}

extern "C" void kernel_launch(void* const* d_in, const int* in_sizes, int n_in,
                              void* d_out, int out_size, void* d_ws, size_t ws_size,
                              hipStream_t stream) {
    const float* x     = (const float*)d_in[0];  // [N,3]
    const int*   batch = (const int*)d_in[1];    // [N]
    const float* v     = (const float*)d_in[2];  // [3,32]
    const float* lin   = (const float*)d_in[3];  // [32]
    float* out = (float*)d_out;                  // [128,32,32]

    const int N = in_sizes[1];

    zero_out_kernel<<<(out_size + 255) / 256, 256, 0, stream>>>(out, out_size);

    const int nblocks = (N + CHUNK - 1) / CHUNK;
    ect_kernel<<<nblocks, 256, 0, stream>>>(x, batch, v, lin, out, N);
}

// Round 9
// 91.226 us; speedup vs baseline: 1.1090x; 1.0737x over previous
//
#include <hip/hip_runtime.h>

// ECT: ect[b,s,t] = sum_{i: batch[i]==b} sigmoid(lin[s] - <x_i, v_t>)
// N=200000, F=3, T=32, S=32, B=128. Output [B,S,T] f32.
//
// sigmoid(lin - nh) = 1/(1 + E*c),  E = exp2(x . (v*log2e)),  c = exp(-lin).
// Paired reciprocal: r = rcp(w0*w1) -> sig0 = r*w1, sig1 = r*w0.
// Block-uniform x/batch reads -> scalar loads (no LDS; r6/r8 showed the
// broadcast mechanism is not the limiter).
//
// r8 diagnosis: latency-bound at 2.4 waves/SIMD (Occupancy 29%, VALUBusy 39%,
// issue floor ~10 us vs 44 us measured). Grid was 1563 blocks = 6 blocks/CU.
// Fix: CHUNK 128 -> 64  => 3125 blocks = 12.2 blocks/CU -> ~3x concurrent
// waves/SIMD to cover the ~130-cyc per-iteration dependence chain.

#define CHUNK 64
#define TT 32
#define SS 32
#define LOG2E 1.4426950408889634f

__global__ void zero_out_kernel(float* __restrict__ out, int n) {
    int i = blockIdx.x * blockDim.x + threadIdx.x;
    if (i < n) out[i] = 0.0f;
}

__global__ __launch_bounds__(256) void ect_kernel(
    const float* __restrict__ x, const int* __restrict__ batch,
    const float* __restrict__ v, const float* __restrict__ lin,
    float* __restrict__ out, int N) {

    const int tid  = threadIdx.x;
    const int base = blockIdx.x * CHUNK;
    const int cnt  = min(CHUNK, N - base);
    if (cnt <= 0) return;  // uniform across block

    const int t      = tid & 31;
    const int s_base = (tid >> 5) * 4;

    // Pre-scaled direction so E = exp2(<x, v'>) needs no extra multiply.
    const float v0 = v[t] * LOG2E;
    const float v1 = v[TT + t] * LOG2E;
    const float v2 = v[2 * TT + t] * LOG2E;
    const float c0 = __builtin_amdgcn_exp2f(-lin[s_base + 0] * LOG2E);
    const float c1 = __builtin_amdgcn_exp2f(-lin[s_base + 1] * LOG2E);
    const float c2 = __builtin_amdgcn_exp2f(-lin[s_base + 2] * LOG2E);
    const float c3 = __builtin_amdgcn_exp2f(-lin[s_base + 3] * LOG2E);

    const float* __restrict__ xc = x + 3 * (size_t)base;  // block-uniform base
    const int*   __restrict__ bc = batch + base;

    const int out_off = s_base * TT + t;  // + b*S*T

    float a0 = 0.f, a1 = 0.f, a2 = 0.f, a3 = 0.f;

    const int b_first = bc[0];
    const int b_last  = bc[cnt - 1];

    if (b_first == b_last) {
        // Hot path (~96% of blocks): whole chunk in one graph; uniform s_loads.
        #pragma unroll 4
        for (int j = 0; j < cnt; ++j) {
            float s0 = xc[3 * j], s1 = xc[3 * j + 1], s2 = xc[3 * j + 2];
            float E  = __builtin_amdgcn_exp2f(fmaf(s2, v2, fmaf(s1, v1, s0 * v0)));
            float w0 = fmaf(E, c0, 1.0f);
            float w1 = fmaf(E, c1, 1.0f);
            float r01 = __builtin_amdgcn_rcpf(w0 * w1);
            a0 = fmaf(r01, w1, a0);
            a1 = fmaf(r01, w0, a1);
            float w2 = fmaf(E, c2, 1.0f);
            float w3 = fmaf(E, c3, 1.0f);
            float r23 = __builtin_amdgcn_rcpf(w2 * w3);
            a2 = fmaf(r23, w3, a2);
            a3 = fmaf(r23, w2, a3);
        }
        float* o = out + b_first * (SS * TT) + out_off;
        atomicAdd(o +  0, a0);
        atomicAdd(o + 32, a1);
        atomicAdd(o + 64, a2);
        atomicAdd(o + 96, a3);
    } else {
        // Chunk spans graph boundary (~4% of blocks): flush on transition.
        int cur_b = b_first;
        for (int j = 0; j < cnt; ++j) {
            int b = bc[j];  // uniform
            if (b != cur_b) {
                float* o = out + cur_b * (SS * TT) + out_off;
                atomicAdd(o +  0, a0);
                atomicAdd(o + 32, a1);
                atomicAdd(o + 64, a2);
                atomicAdd(o + 96, a3);
                a0 = a1 = a2 = a3 = 0.f;
                cur_b = b;
            }
            float s0 = xc[3 * j], s1 = xc[3 * j + 1], s2 = xc[3 * j + 2];
            float E  = __builtin_amdgcn_exp2f(fmaf(s2, v2, fmaf(s1, v1, s0 * v0)));
            float w0 = fmaf(E, c0, 1.0f);
            float w1 = fmaf(E, c1, 1.0f);
            float r01 = __builtin_amdgcn_rcpf(w0 * w1);
            a0 = fmaf(r01, w1, a0);
            a1 = fmaf(r01, w0, a1);
            float w2 = fmaf(E, c2, 1.0f);
            float w3 = fmaf(E, c3, 1.0f);
            float r23 = __builtin_amdgcn_rcpf(w2 * w3);
            a2 = fmaf(r23, w3, a2);
            a3 = fmaf(r23, w2, a3);
        }
        float* o = out + cur_b * (SS * TT) + out_off;
        atomicAdd(o +  0, a0);
        atomicAdd(o + 32, a1);
        atomicAdd(o + 64, a2);
        atomicAdd(o + 96, a3);
    }
}

extern "C" void kernel_launch(void* const* d_in, const int* in_sizes, int n_in,
                              void* d_out, int out_size, void* d_ws, size_t ws_size,
                              hipStream_t stream) {
    const float* x     = (const float*)d_in[0];  // [N,3]
    const int*   batch = (const int*)d_in[1];    // [N]
    const float* v     = (const float*)d_in[2];  // [3,32]
    const float* lin   = (const float*)d_in[3];  // [32]
    float* out = (float*)d_out;                  // [128,32,32]

    const int N = in_sizes[1];

    zero_out_kernel<<<(out_size + 255) / 256, 256, 0, stream>>>(out, out_size);

    const int nblocks = (N + CHUNK - 1) / CHUNK;
    ect_kernel<<<nblocks, 256, 0, stream>>>(x, batch, v, lin, out, N);
}